// Round 3
// baseline (212.528 us; speedup 1.0000x reference)
//
#include <hip/hip_runtime.h>
#include <hip/hip_bf16.h>

// T=5 B=512 NA=16 S=64 A=16 HID=64 H=4 FD=256 LAT=128 N=8192 FIN=80
// R19 vs R18 (190.2 us; k_gat regressed to 61-69, Occ 21%): G=5 batching
// reverted -- k_gat restored to the proven R17 form (grid 2560, 5 blocks/CU,
// 55.7 us measured). R17/R18 jointly showed k_gat is latency/VALU-floor
// bound (~21-25 us VALU issue in all variants), so this round targets the
// HIDDEN cost: k_stage2's qkv phase issued 640 broadcast ds_read_b128 per
// thread (~25-40 us of LDS pipe per CU). Rewrite: one batch row per block
// (grid 512x256); seqf rows read as wave-uniform global loads (compiler
// scalarizes to s_load / L1 broadcast -- zero LDS for x); weights as 3
// coalesced f4 streams (q/k/v col n). k/v/q written straight to 13.5 KB LDS.
// Attention/out_proj/heads math and accumulation order unchanged.
// k_pre = R17. Same algebra (R10).

__device__ __forceinline__ float wave_sum64(float v) {
    #pragma unroll
    for (int off = 32; off > 0; off >>= 1) v += __shfl_xor(v, off, 64);
    return v;
}
__device__ __forceinline__ float wave_max64(float v) {
    #pragma unroll
    for (int off = 32; off > 0; off >>= 1) v = fmaxf(v, __shfl_xor(v, off, 64));
    return v;
}

#define FMA4(acc, wv, zv) \
    acc = fmaf((wv).x, (zv).x, acc); acc = fmaf((wv).y, (zv).y, acc); \
    acc = fmaf((wv).z, (zv).z, acc); acc = fmaf((wv).w, (zv).w, acc);

// ---------------- prologue: packed transposes + u1/ud1/pa0/pd0 -------------
// Packed layouts (all float4-consumable by column n):
//   W0sPK: [16][256][4]  float off (k>>2)*1024 + n*4 + (k&3) = W0s[k][n]
//   W0aPK: [4][256][4]   +16384
//   W1PK : [64][256][4]  +20480
//   wipPK: [64][768][4]  +86016
//   wopPK: [64][256][4]  +282624
//   whPK : [64][320][4]  +348160  (mean|logvar|belief rows o<320)
__global__ __launch_bounds__(256) void k_pre(
    const float* __restrict__ w0, const float* __restrict__ w1,
    const float* __restrict__ wip, const float* __restrict__ wop,
    const float* __restrict__ wm, const float* __restrict__ wlv,
    const float* __restrict__ wb,
    const float* __restrict__ as0, const float* __restrict__ ad0,
    const float* __restrict__ as1, const float* __restrict__ ad1,
    float* __restrict__ tws,
    float* __restrict__ u1, float* __restrict__ ud1,
    float* __restrict__ pa0, float* __restrict__ pd0)
{
    const int tid = threadIdx.x;
    if (blockIdx.x < 1680) {
        int i = blockIdx.x * 256 + tid;          // 1680*256 = 430080 exact
        float v; int d;
        if (i < 16384) {                         // W0sPK
            int k = i & 63, nn = i >> 6;
            v = w0[nn * 80 + k];
            d = (k >> 2) * 1024 + nn * 4 + (k & 3);
        } else if (i < 20480) {                  // W0aPK
            int j = i - 16384; int k = j & 15, nn = j >> 4;
            v = w0[nn * 80 + 64 + k];
            d = 16384 + (k >> 2) * 1024 + nn * 4 + (k & 3);
        } else if (i < 86016) {                  // W1PK
            int j = i - 20480; int k = j & 255, nn = j >> 8;
            v = w1[nn * 256 + k];
            d = 20480 + (k >> 2) * 1024 + nn * 4 + (k & 3);
        } else if (i < 282624) {                 // wipPK
            int j = i - 86016; int k = j & 255, nn = j >> 8;   // nn < 768
            v = wip[nn * 256 + k];
            d = 86016 + (k >> 2) * 3072 + nn * 4 + (k & 3);
        } else if (i < 348160) {                 // wopPK
            int j = i - 282624; int k = j & 255, nn = j >> 8;
            v = wop[nn * 256 + k];
            d = 282624 + (k >> 2) * 1024 + nn * 4 + (k & 3);
        } else {                                 // whPK: mean|logvar|belief
            int j = i - 348160; int k = j & 255, o = j >> 8;   // o < 320
            if (o < 128)      v = wm[o * 256 + k];
            else if (o < 256) v = wlv[(o - 128) * 256 + k];
            else              v = wb[(o - 256) * 256 + k];
            d = 348160 + (k >> 2) * 1280 + o * 4 + (k & 3);
        }
        tws[d] = v;
        return;
    }
    for (int q = 0; q < 4; q++) {
        int idx = q * 256 + tid;                 // 1024
        int h = idx >> 8, k = idx & 255;
        float su = 0.f, sd = 0.f;
        for (int c = 0; c < 64; c++) {
            float wv = w1[(h * 64 + c) * 256 + k];
            su = fmaf(as1[h * 64 + c], wv, su);
            sd = fmaf(ad1[h * 64 + c], wv, sd);
        }
        u1[idx] = su; ud1[idx] = sd;
    }
    if (tid < 64) {
        int h = tid >> 4, k = tid & 15;
        float su = 0.f, sd = 0.f;
        for (int c = 0; c < 64; c++) {
            float wv = w0[(h * 64 + c) * 80 + 64 + k];
            su = fmaf(as0[h * 64 + c], wv, su);
            sd = fmaf(ad0[h * 64 + c], wv, sd);
        }
        pa0[tid] = su; pd0[tid] = sd;
    }
}

// ---------------- stage 1: 2-layer GAT, one block per (b,g), 5 barriers -----
// (R17 verbatim: 2560 blocks, 256 threads; 28288 B LDS -> 5 blocks/CU.)
__global__ __launch_bounds__(256, 5) void k_gat(
    const float* __restrict__ sig,    // (T,B,64)
    const float* __restrict__ nact,   // (T,B,256)
    const float* __restrict__ W0sPK,  // packed [16][256][4]
    const float* __restrict__ W0aPK,  // packed [4][256][4]
    const float* __restrict__ W1PK,   // packed [64][256][4]
    const float* __restrict__ u1g, const float* __restrict__ ud1g,   // [4][256]
    const float* __restrict__ pa0g, const float* __restrict__ pd0g,  // [4][16]
    const float* __restrict__ as0, const float* __restrict__ ad0,
    const float* __restrict__ b0, const float* __restrict__ b1,
    float* __restrict__ seqf)         // (2560,256)
{
    __shared__ __align__(16) char smem[28288];
    float* actL    = (float*)(smem + 0);       // [16][16]
    float* sigL    = (float*)(smem + 1024);    // [64]
    float* es0w    = (float*)(smem + 1280);    // [4][16]  (per-wave)
    float* ed0w    = (float*)(smem + 1536);    // [4][16]
    float* espL    = (float*)(smem + 1792);    // [16][4][4]
    float* es1L    = (float*)(smem + 2816);    // [16][4]
    float* edpL    = (float*)(smem + 3072);    // [4][4]
    float* alpha1L = (float*)(smem + 3136);    // [4][16]
    float* a0L     = (float*)(smem + 3392);    // [4][16][16]
    float* zL      = (float*)(smem + 7488);    // [4][260]
    float* x1L     = (float*)(smem + 11648);   // [16][260]

    const int tid = threadIdx.x;
    const int bg = blockIdx.x;
    const int b = bg / 5, g = bg - b * 5;
    const int n = tid, w = tid >> 6, lane = tid & 63;

    const float4* W0sPK4 = (const float4*)W0sPK;

    // prefetch: W0s batch 0 (k=0..31), W0a (k=0..15), as0/ad0 scalars
    float4 wv0[8];
    #pragma unroll
    for (int j = 0; j < 8; j++) wv0[j] = W0sPK4[j * 256 + n];
    float4 wa[4];
    {
        const float4* W0aPK4 = (const float4*)W0aPK;
        #pragma unroll
        for (int q = 0; q < 4; q++) wa[q] = W0aPK4[q * 256 + n];
    }
    const float as0n = as0[n];
    const float ad0n = ad0[n];

    // P1: input loads (float4)
    if (tid < 16)
        ((float4*)sigL)[tid] = ((const float4*)(sig + (g * 512 + b) * 64))[tid];
    if (tid < 64)
        ((float4*)actL)[tid] = ((const float4*)(nact + (g * 512 + b) * 256))[tid];
    __syncthreads();                                       // barrier 1

    // P2: S[n] = sig . W0s[:,n]  (k-order preserved)
    float S = 0.f;
    {
        const float4* sig4 = (const float4*)sigL;
        #pragma unroll
        for (int j = 0; j < 8; j++) {
            float4 sv = sig4[j];
            S = fmaf(wv0[j].x, sv.x, S);
            S = fmaf(wv0[j].y, sv.y, S);
            S = fmaf(wv0[j].z, sv.z, S);
            S = fmaf(wv0[j].w, sv.w, S);
        }
        float4 wv1[8];
        #pragma unroll
        for (int j = 0; j < 8; j++) wv1[j] = W0sPK4[(8 + j) * 256 + n];
        #pragma unroll
        for (int j = 0; j < 8; j++) {
            float4 sv = sig4[8 + j];
            S = fmaf(wv1[j].x, sv.x, S);
            S = fmaf(wv1[j].y, sv.y, S);
            S = fmaf(wv1[j].z, sv.z, S);
            S = fmaf(wv1[j].w, sv.w, S);
        }
    }
    // issue pa0/pd0 broadcast loads before the shuffle chains cover them
    const int m3 = lane >> 2, q3 = lane & 3;
    const float4 pv = ((const float4*)(pa0g + w * 16))[q3];
    const float4 dv = ((const float4*)(pd0g + w * 16))[q3];

    const float sS = wave_sum64(S * as0n);   // full sum in every lane
    const float dS = wave_sum64(S * ad0n);

    // P3 (64 lanes): es0w[w][m] = (m==0)*sS + act[m].pa0[w]
    {
        const float4 av = ((const float4*)(actL + m3 * 16))[q3];
        float su = av.x * pv.x;
        su = fmaf(av.y, pv.y, su); su = fmaf(av.z, pv.z, su); su = fmaf(av.w, pv.w, su);
        float sd = av.x * dv.x;
        sd = fmaf(av.y, dv.y, sd); sd = fmaf(av.z, dv.z, sd); sd = fmaf(av.w, dv.w, sd);
        su += __shfl_xor(su, 1, 64); su += __shfl_xor(su, 2, 64);
        sd += __shfl_xor(sd, 1, 64); sd += __shfl_xor(sd, 2, 64);
        if (q3 == 0) {
            es0w[w * 16 + m3] = su + ((m3 == 0) ? sS : 0.f);
            ed0w[w * 16 + m3] = sd + ((m3 == 0) ? dS : 0.f);
        }
    }
    // P4 (64 lanes, wave-synchronous): alpha0 row j, s-quarter q
    {
        const int j = lane >> 2, q = lane & 3;
        const float ej = ed0w[w * 16 + j];
        const float4 ev = ((const float4*)(es0w + w * 16))[q];
        float e0 = ev.x + ej; e0 = (e0 >= 0.f) ? e0 : 0.2f * e0;
        float e1 = ev.y + ej; e1 = (e1 >= 0.f) ? e1 : 0.2f * e1;
        float e2 = ev.z + ej; e2 = (e2 >= 0.f) ? e2 : 0.2f * e2;
        float e3 = ev.w + ej; e3 = (e3 >= 0.f) ? e3 : 0.2f * e3;
        float mx = fmaxf(fmaxf(e0, e1), fmaxf(e2, e3));
        mx = fmaxf(mx, __shfl_xor(mx, 1, 64));
        mx = fmaxf(mx, __shfl_xor(mx, 2, 64));
        e0 = __expf(e0 - mx); e1 = __expf(e1 - mx);
        e2 = __expf(e2 - mx); e3 = __expf(e3 - mx);
        float s = e0 + e1 + e2 + e3;
        s += __shfl_xor(s, 1, 64); s += __shfl_xor(s, 2, 64);
        float inv = 1.f / s;
        ((float4*)(a0L + (w << 8) + j * 16))[q] =
            make_float4(e0 * inv, e1 * inv, e2 * inv, e3 * inv);
    }
    // a0L[w] written and consumed by wave w only -> no block barrier

    // P56: xl0r[s] = (s==0)*S + act[s].W0a[:,n]; x1r[j] via b128 a0L[w]
    float x1r[16];
    {
        const float4* act4 = (const float4*)actL;
        float xl0r[16];
        #pragma unroll
        for (int s = 0; s < 16; s++) {
            float a = 0.f;
            #pragma unroll
            for (int q = 0; q < 4; q++) {
                float4 av = act4[s * 4 + q];
                FMA4(a, av, wa[q]);
            }
            xl0r[s] = a;
        }
        xl0r[0] += S;
        const float b0v = b0[n];
        const float4* a04 = (const float4*)(a0L + (w << 8));
        #pragma unroll
        for (int j = 0; j < 16; j++) {
            float acc = b0v;
            #pragma unroll
            for (int s4 = 0; s4 < 4; s4++) {
                float4 a4 = a04[j * 4 + s4];          // broadcast b128
                acc = fmaf(a4.x, xl0r[s4 * 4 + 0], acc);
                acc = fmaf(a4.y, xl0r[s4 * 4 + 1], acc);
                acc = fmaf(a4.z, xl0r[s4 * 4 + 2], acc);
                acc = fmaf(a4.w, xl0r[s4 * 4 + 3], acc);
            }
            x1r[j] = fmaxf(acc, 0.f);
            x1L[j * 260 + n] = x1r[j];
        }
    }
    __syncthreads();                                       // barrier 2

    // P7: es1/ed1 partials; u1/ud1 direct from global (L1 broadcast)
    {
        const int m = tid & 15, h = (tid >> 4) & 3, p = tid >> 6;
        const float4* x4p = (const float4*)(x1L + m * 260 + p * 64);
        const float4* u4p = ((const float4*)u1g) + h * 64 + p * 16;
        float a = 0.f;
        #pragma unroll
        for (int i = 0; i < 16; i++) {
            float4 xv = x4p[i], uv = u4p[i];
            FMA4(a, xv, uv);
        }
        espL[m * 16 + h * 4 + p] = a;
        if (m == 0) {
            const float4* ud4p = ((const float4*)ud1g) + h * 64 + p * 16;
            float ad = 0.f;
            #pragma unroll
            for (int i = 0; i < 16; i++) {
                float4 xv = x4p[i], uv = ud4p[i];
                FMA4(ad, xv, uv);
            }
            edpL[h * 4 + p] = ad;
        }
    }
    __syncthreads();                                       // barrier 3

    // P8 (wave 0, wave-synchronous): es1 sums then alpha1 (16 lanes)
    if (w == 0) {
        {
            const int m2 = lane >> 2, h = lane & 3;
            const float* e = espL + m2 * 16 + h * 4;
            es1L[m2 * 4 + h] = e[0] + e[1] + e[2] + e[3];
        }
        if (lane < 16) {
            const int h = lane >> 2, q = lane & 3;
            float ej = edpL[h * 4] + edpL[h * 4 + 1] + edpL[h * 4 + 2] + edpL[h * 4 + 3];
            float e[4]; float mx = -1e30f;
            #pragma unroll
            for (int r = 0; r < 4; r++) {
                float x = es1L[(q * 4 + r) * 4 + h] + ej;
                x = (x >= 0.f) ? x : 0.2f * x;
                e[r] = x; mx = fmaxf(mx, x);
            }
            mx = fmaxf(mx, __shfl_xor(mx, 1, 64));
            mx = fmaxf(mx, __shfl_xor(mx, 2, 64));
            float s = 0.f;
            #pragma unroll
            for (int r = 0; r < 4; r++) { e[r] = __expf(e[r] - mx); s += e[r]; }
            s += __shfl_xor(s, 1, 64);
            s += __shfl_xor(s, 2, 64);
            float inv = 1.f / s;
            ((float4*)(alpha1L + h * 16 + q * 4))[0] =
                make_float4(e[0] * inv, e[1] * inv, e[2] * inv, e[3] * inv);
        }
    }
    __syncthreads();                                       // barrier 4

    // P9: z[hh][n] = sum_s alpha1[hh][s] * x1r[s]; W1 batch 0 + b1 prefetch
    const float4* W1PK4 = (const float4*)W1PK;
    float4 w1pf[8];
    #pragma unroll
    for (int j = 0; j < 8; j++) w1pf[j] = W1PK4[j * 256 + n];
    const float b1v = b1[n];
    {
        const float4* a14 = (const float4*)alpha1L;
        #pragma unroll
        for (int hh = 0; hh < 4; hh++) {
            float zv = 0.f;
            #pragma unroll
            for (int s4 = 0; s4 < 4; s4++) {
                float4 a4 = a14[hh * 4 + s4];         // broadcast b128
                zv = fmaf(a4.x, x1r[s4 * 4 + 0], zv);
                zv = fmaf(a4.y, x1r[s4 * 4 + 1], zv);
                zv = fmaf(a4.z, x1r[s4 * 4 + 2], zv);
                zv = fmaf(a4.w, x1r[s4 * 4 + 3], zv);
            }
            zL[hh * 260 + n] = zv;
        }
    }
    __syncthreads();                                       // barrier 5

    // P10: seq[bg][n] = relu(z[w] . W1[:,n] + b1[n]); k-order preserved
    {
        const float4* zh = (const float4*)(zL + w * 260);
        float acc = b1v;
        #pragma unroll
        for (int j = 0; j < 8; j++) {
            float4 z4 = zh[j];
            FMA4(acc, w1pf[j], z4);
        }
        #pragma unroll
        for (int io = 1; io < 8; io++) {
            float4 wv[8];
            #pragma unroll
            for (int j = 0; j < 8; j++) wv[j] = W1PK4[(io * 8 + j) * 256 + n];
            #pragma unroll
            for (int j = 0; j < 8; j++) {
                float4 z4 = zh[io * 8 + j];
                FMA4(acc, wv[j], z4);
            }
        }
        seqf[bg * 256 + n] = fmaxf(acc, 0.f);
    }
}

// ---------------- stage 2: qkv + attention + out_proj + heads (v2) ---------
// One batch row per block (grid 512, 256 threads). seqf rows are read as
// wave-uniform global loads (scalarizable) -- no LDS staging of x at all.
// Thread n computes q/k/v column n (3 coalesced f4 weight streams).
__global__ __launch_bounds__(256) void k_stage2(
    const float* __restrict__ seqf,   // (2560,256)
    const float* __restrict__ wipPK,  // packed [64][768][4]
    const float* __restrict__ bip,
    const float* __restrict__ wopPK,  // packed [64][256][4]
    const float* __restrict__ bop,
    const float* __restrict__ whPK,   // packed [64][320][4]
    const float* __restrict__ bm, const float* __restrict__ blv,
    const float* __restrict__ bb,
    float* __restrict__ out)
{
    __shared__ float kL[5][256], vL[5][256], qL[256];
    __shared__ float ctxL[256], featL[256];
    __shared__ float beliefL[64];
    const int tid = threadIdx.x;
    const int b = blockIdx.x;        // 0..511
    const int n = tid;

    // qkv: x rows wave-uniform (scalar), weights coalesced f4.
    // Accumulation order identical to reference: k ascending, x->y->z->w.
    {
        const float4* sq = (const float4*)(seqf + b * 1280);  // sq[t*64+k4]
        const float4* wPK = (const float4*)wipPK;
        float aq = 0.f;
        float ak0 = 0.f, ak1 = 0.f, ak2 = 0.f, ak3 = 0.f, ak4 = 0.f;
        float av0 = 0.f, av1 = 0.f, av2 = 0.f, av3 = 0.f, av4 = 0.f;
        #pragma unroll 4
        for (int k4 = 0; k4 < 64; k4++) {
            float4 wq = wPK[k4 * 768 + n];
            float4 wk = wPK[k4 * 768 + 256 + n];
            float4 wv = wPK[k4 * 768 + 512 + n];
            float4 x0 = sq[k4],       x1 = sq[64 + k4], x2 = sq[128 + k4];
            float4 x3 = sq[192 + k4], x4 = sq[256 + k4];
            FMA4(aq, wq, x4);
            FMA4(ak0, wk, x0); FMA4(ak1, wk, x1); FMA4(ak2, wk, x2);
            FMA4(ak3, wk, x3); FMA4(ak4, wk, x4);
            FMA4(av0, wv, x0); FMA4(av1, wv, x1); FMA4(av2, wv, x2);
            FMA4(av3, wv, x3); FMA4(av4, wv, x4);
        }
        qL[n] = aq + bip[n];
        const float bk = bip[256 + n], bv = bip[512 + n];
        kL[0][n] = ak0 + bk; kL[1][n] = ak1 + bk; kL[2][n] = ak2 + bk;
        kL[3][n] = ak3 + bk; kL[4][n] = ak4 + bk;
        vL[0][n] = av0 + bv; vL[1][n] = av1 + bv; vL[2][n] = av2 + bv;
        vL[3][n] = av3 + bv; vL[4][n] = av4 + bv;
    }
    __syncthreads();

    // attention at q=4 (wave = head, 64-lane dot per head; mask cancels)
    {
        float q4 = qL[n];
        float sc[5];
        #pragma unroll
        for (int t = 0; t < 5; t++)
            sc[t] = wave_sum64(q4 * kL[t][n]) * 0.125f;
        float m = sc[0];
        #pragma unroll
        for (int t = 1; t < 5; t++) m = fmaxf(m, sc[t]);
        float p[5], sum = 0.f;
        #pragma unroll
        for (int t = 0; t < 5; t++) { p[t] = __expf(sc[t] - m); sum += p[t]; }
        float inv = 1.f / sum, cv = 0.f;
        #pragma unroll
        for (int t = 0; t < 5; t++) cv = fmaf(p[t], vL[t][n], cv);
        ctxL[n] = cv * inv;
    }
    __syncthreads();

    // out_proj
    {
        const float4* wPK = (const float4*)wopPK + n;
        const float4* c4 = (const float4*)ctxL;
        float acc = 0.f;
        #pragma unroll 8
        for (int k4 = 0; k4 < 64; k4++) {
            float4 wv = wPK[k4 * 256], cv = c4[k4];
            FMA4(acc, wv, cv);
        }
        featL[n] = acc + bop[n];
    }
    __syncthreads();

    // heads: thread n -> j=n (mean/logvar); n<64 also -> j=256+n (belief)
    {
        const float4* f4 = (const float4*)featL;
        const float4* wPK = (const float4*)whPK + n;
        float acc = 0.f;
        #pragma unroll 8
        for (int k4 = 0; k4 < 64; k4++) {
            float4 wv = wPK[k4 * 320], fv = f4[k4];
            FMA4(acc, wv, fv);
        }
        if (n < 128) out[b * 128 + n] = acc + bm[n];
        else         out[65536 + b * 128 + (n - 128)] = acc + blv[n - 128];
        if (n < 64) {
            const float4* w2 = (const float4*)whPK + 256 + n;
            float acc2 = 0.f;
            #pragma unroll 8
            for (int k4 = 0; k4 < 64; k4++) {
                float4 wv = w2[k4 * 320], fv = f4[k4];
                FMA4(acc2, wv, fv);
            }
            beliefL[n] = acc2 + bb[n];
        }
    }
    __syncthreads();

    // belief softmax (wave 0)
    if (tid < 64) {
        float lg = beliefL[tid];
        float m = wave_max64(lg);
        float e = __expf(lg - m);
        float s = wave_sum64(e);
        out[131072 + b * 64 + tid] = e / s;
    }
}

// ---------------------------------------------------------------------------
extern "C" void kernel_launch(void* const* d_in, const int* in_sizes, int n_in,
                              void* d_out, int out_size, void* d_ws, size_t ws_size,
                              hipStream_t stream) {
    const float* sig  = (const float*)d_in[0];
    const float* nact = (const float*)d_in[1];
    const float* w0   = (const float*)d_in[2];
    const float* as0  = (const float*)d_in[3];
    const float* ad0  = (const float*)d_in[4];
    const float* b0   = (const float*)d_in[5];
    const float* w1   = (const float*)d_in[6];
    const float* as1  = (const float*)d_in[7];
    const float* ad1  = (const float*)d_in[8];
    const float* b1   = (const float*)d_in[9];
    const float* wip  = (const float*)d_in[10];
    const float* bip  = (const float*)d_in[11];
    const float* wop  = (const float*)d_in[12];
    const float* bop  = (const float*)d_in[13];
    const float* wm   = (const float*)d_in[14];
    const float* bm   = (const float*)d_in[15];
    const float* wlv  = (const float*)d_in[16];
    const float* blv  = (const float*)d_in[17];
    const float* wb   = (const float*)d_in[18];
    const float* bb   = (const float*)d_in[19];
    // d_in[20] = edge_index (deterministic complete graph) — unused.

    // ws layout (floats): seqf + packed transposes + folds. ~4.35 MB
    float* ws    = (float*)d_ws;
    float* seqf  = ws;                 // 655360
    float* tws   = ws + 655360;        // 430080:
    float* W0sPK = tws;                //   16384
    float* W0aPK = tws + 16384;        //   4096
    float* W1PK  = tws + 20480;        //   65536
    float* wipPK = tws + 86016;        //   196608
    float* wopPK = tws + 282624;       //   65536
    float* whPK  = tws + 348160;       //   81920
    float* u1    = ws + 1085440;       // 1024
    float* ud1   = ws + 1086464;       // 1024
    float* pa0   = ws + 1087488;       // 64
    float* pd0   = ws + 1087552;       // 64

    k_pre   <<<1681, 256, 0, stream>>>(w0, w1, wip, wop, wm, wlv, wb,
                                       as0, ad0, as1, ad1,
                                       tws, u1, ud1, pa0, pd0);
    k_gat   <<<2560, 256, 0, stream>>>(sig, nact, W0sPK, W0aPK, W1PK,
                                       u1, ud1, pa0, pd0, as0, ad0, b0, b1, seqf);
    k_stage2<<<512, 256, 0, stream>>>(seqf, wipPK, bip, wopPK, bop, whPK,
                                      bm, blv, bb, (float*)d_out);
}

// Round 4
// 182.286 us; speedup vs baseline: 1.1659x; 1.1659x over previous
//
#include <hip/hip_runtime.h>
#include <hip/hip_bf16.h>

// T=5 B=512 NA=16 S=64 A=16 HID=64 H=4 FD=256 LAT=128 N=8192 FIN=80
// R20 vs R19 (212.5 us): two reverts + one fix.
// (1) k_stage2 reverted to R17 form (256 blocks x 768): R19's 512x256 split
//     doubled weight L2 re-stream (344->688 MB) and regressed total ~+20 us.
// (2) k_pre fold straggler fixed: u1/ud1 (1024 outs x 64-deep) was ONE
//     rolled-loop block (~dependent 250cyc L2 loads, est 30-50 us) that
//     serialized before k_gat. Now 4 parallel blocks (one per head) + 1
//     block for pa0/pd0, c-loop fully unrolled -> 64 loads in flight.
// (3) k_gat = R17/R19 verbatim (55 us stable, VALUBusy 38%, Occ 41%).
// Same algebra (R10); accumulation order preserved everywhere.

__device__ __forceinline__ float wave_sum64(float v) {
    #pragma unroll
    for (int off = 32; off > 0; off >>= 1) v += __shfl_xor(v, off, 64);
    return v;
}
__device__ __forceinline__ float wave_max64(float v) {
    #pragma unroll
    for (int off = 32; off > 0; off >>= 1) v = fmaxf(v, __shfl_xor(v, off, 64));
    return v;
}

#define FMA4(acc, wv, zv) \
    acc = fmaf((wv).x, (zv).x, acc); acc = fmaf((wv).y, (zv).y, acc); \
    acc = fmaf((wv).z, (zv).z, acc); acc = fmaf((wv).w, (zv).w, acc);

// ---------------- prologue: packed transposes + u1/ud1/pa0/pd0 -------------
// Packed layouts (all float4-consumable by column n):
//   W0sPK: [16][256][4]  float off (k>>2)*1024 + n*4 + (k&3) = W0s[k][n]
//   W0aPK: [4][256][4]   +16384
//   W1PK : [64][256][4]  +20480
//   wipPK: [64][768][4]  +86016
//   wopPK: [64][256][4]  +282624
//   whPK : [64][320][4]  +348160  (mean|logvar|belief rows o<320)
// Blocks 0..1679: transpose. 1680..1683: u1/ud1 head h. 1684: pa0/pd0.
__global__ __launch_bounds__(256) void k_pre(
    const float* __restrict__ w0, const float* __restrict__ w1,
    const float* __restrict__ wip, const float* __restrict__ wop,
    const float* __restrict__ wm, const float* __restrict__ wlv,
    const float* __restrict__ wb,
    const float* __restrict__ as0, const float* __restrict__ ad0,
    const float* __restrict__ as1, const float* __restrict__ ad1,
    float* __restrict__ tws,
    float* __restrict__ u1, float* __restrict__ ud1,
    float* __restrict__ pa0, float* __restrict__ pd0)
{
    const int tid = threadIdx.x;
    if (blockIdx.x < 1680) {
        int i = blockIdx.x * 256 + tid;          // 1680*256 = 430080 exact
        float v; int d;
        if (i < 16384) {                         // W0sPK
            int k = i & 63, nn = i >> 6;
            v = w0[nn * 80 + k];
            d = (k >> 2) * 1024 + nn * 4 + (k & 3);
        } else if (i < 20480) {                  // W0aPK
            int j = i - 16384; int k = j & 15, nn = j >> 4;
            v = w0[nn * 80 + 64 + k];
            d = 16384 + (k >> 2) * 1024 + nn * 4 + (k & 3);
        } else if (i < 86016) {                  // W1PK
            int j = i - 20480; int k = j & 255, nn = j >> 8;
            v = w1[nn * 256 + k];
            d = 20480 + (k >> 2) * 1024 + nn * 4 + (k & 3);
        } else if (i < 282624) {                 // wipPK
            int j = i - 86016; int k = j & 255, nn = j >> 8;   // nn < 768
            v = wip[nn * 256 + k];
            d = 86016 + (k >> 2) * 3072 + nn * 4 + (k & 3);
        } else if (i < 348160) {                 // wopPK
            int j = i - 282624; int k = j & 255, nn = j >> 8;
            v = wop[nn * 256 + k];
            d = 282624 + (k >> 2) * 1024 + nn * 4 + (k & 3);
        } else {                                 // whPK: mean|logvar|belief
            int j = i - 348160; int k = j & 255, o = j >> 8;   // o < 320
            if (o < 128)      v = wm[o * 256 + k];
            else if (o < 256) v = wlv[(o - 128) * 256 + k];
            else              v = wb[(o - 256) * 256 + k];
            d = 348160 + (k >> 2) * 1280 + o * 4 + (k & 3);
        }
        tws[d] = v;
        return;
    }
    if (blockIdx.x < 1684) {
        // u1/ud1 for head h: u1[h*256+k] = sum_c as1[h*64+c]*w1[(h*64+c)*256+k]
        const int h = blockIdx.x - 1680;
        const int k = tid;
        float su = 0.f, sd = 0.f;
        #pragma unroll
        for (int c = 0; c < 64; c++) {
            float wv = w1[(h * 64 + c) * 256 + k];
            su = fmaf(as1[h * 64 + c], wv, su);
            sd = fmaf(ad1[h * 64 + c], wv, sd);
        }
        u1[h * 256 + k] = su;
        ud1[h * 256 + k] = sd;
        return;
    }
    // block 1684: pa0/pd0 (64 outputs, 64-deep)
    if (tid < 64) {
        int h = tid >> 4, k = tid & 15;
        float su = 0.f, sd = 0.f;
        #pragma unroll
        for (int c = 0; c < 64; c++) {
            float wv = w0[(h * 64 + c) * 80 + 64 + k];
            su = fmaf(as0[h * 64 + c], wv, su);
            sd = fmaf(ad0[h * 64 + c], wv, sd);
        }
        pa0[tid] = su; pd0[tid] = sd;
    }
}

// ---------------- stage 1: 2-layer GAT, one block per (b,g), 5 barriers -----
// (R17 verbatim: 2560 blocks, 256 threads; 28288 B LDS -> 5 blocks/CU.)
__global__ __launch_bounds__(256, 5) void k_gat(
    const float* __restrict__ sig,    // (T,B,64)
    const float* __restrict__ nact,   // (T,B,256)
    const float* __restrict__ W0sPK,  // packed [16][256][4]
    const float* __restrict__ W0aPK,  // packed [4][256][4]
    const float* __restrict__ W1PK,   // packed [64][256][4]
    const float* __restrict__ u1g, const float* __restrict__ ud1g,   // [4][256]
    const float* __restrict__ pa0g, const float* __restrict__ pd0g,  // [4][16]
    const float* __restrict__ as0, const float* __restrict__ ad0,
    const float* __restrict__ b0, const float* __restrict__ b1,
    float* __restrict__ seqf)         // (2560,256)
{
    __shared__ __align__(16) char smem[28288];
    float* actL    = (float*)(smem + 0);       // [16][16]
    float* sigL    = (float*)(smem + 1024);    // [64]
    float* es0w    = (float*)(smem + 1280);    // [4][16]  (per-wave)
    float* ed0w    = (float*)(smem + 1536);    // [4][16]
    float* espL    = (float*)(smem + 1792);    // [16][4][4]
    float* es1L    = (float*)(smem + 2816);    // [16][4]
    float* edpL    = (float*)(smem + 3072);    // [4][4]
    float* alpha1L = (float*)(smem + 3136);    // [4][16]
    float* a0L     = (float*)(smem + 3392);    // [4][16][16]
    float* zL      = (float*)(smem + 7488);    // [4][260]
    float* x1L     = (float*)(smem + 11648);   // [16][260]

    const int tid = threadIdx.x;
    const int bg = blockIdx.x;
    const int b = bg / 5, g = bg - b * 5;
    const int n = tid, w = tid >> 6, lane = tid & 63;

    const float4* W0sPK4 = (const float4*)W0sPK;

    // prefetch: W0s batch 0 (k=0..31), W0a (k=0..15), as0/ad0 scalars
    float4 wv0[8];
    #pragma unroll
    for (int j = 0; j < 8; j++) wv0[j] = W0sPK4[j * 256 + n];
    float4 wa[4];
    {
        const float4* W0aPK4 = (const float4*)W0aPK;
        #pragma unroll
        for (int q = 0; q < 4; q++) wa[q] = W0aPK4[q * 256 + n];
    }
    const float as0n = as0[n];
    const float ad0n = ad0[n];

    // P1: input loads (float4)
    if (tid < 16)
        ((float4*)sigL)[tid] = ((const float4*)(sig + (g * 512 + b) * 64))[tid];
    if (tid < 64)
        ((float4*)actL)[tid] = ((const float4*)(nact + (g * 512 + b) * 256))[tid];
    __syncthreads();                                       // barrier 1

    // P2: S[n] = sig . W0s[:,n]  (k-order preserved)
    float S = 0.f;
    {
        const float4* sig4 = (const float4*)sigL;
        #pragma unroll
        for (int j = 0; j < 8; j++) {
            float4 sv = sig4[j];
            S = fmaf(wv0[j].x, sv.x, S);
            S = fmaf(wv0[j].y, sv.y, S);
            S = fmaf(wv0[j].z, sv.z, S);
            S = fmaf(wv0[j].w, sv.w, S);
        }
        float4 wv1[8];
        #pragma unroll
        for (int j = 0; j < 8; j++) wv1[j] = W0sPK4[(8 + j) * 256 + n];
        #pragma unroll
        for (int j = 0; j < 8; j++) {
            float4 sv = sig4[8 + j];
            S = fmaf(wv1[j].x, sv.x, S);
            S = fmaf(wv1[j].y, sv.y, S);
            S = fmaf(wv1[j].z, sv.z, S);
            S = fmaf(wv1[j].w, sv.w, S);
        }
    }
    // issue pa0/pd0 broadcast loads before the shuffle chains cover them
    const int m3 = lane >> 2, q3 = lane & 3;
    const float4 pv = ((const float4*)(pa0g + w * 16))[q3];
    const float4 dv = ((const float4*)(pd0g + w * 16))[q3];

    const float sS = wave_sum64(S * as0n);   // full sum in every lane
    const float dS = wave_sum64(S * ad0n);

    // P3 (64 lanes): es0w[w][m] = (m==0)*sS + act[m].pa0[w]
    {
        const float4 av = ((const float4*)(actL + m3 * 16))[q3];
        float su = av.x * pv.x;
        su = fmaf(av.y, pv.y, su); su = fmaf(av.z, pv.z, su); su = fmaf(av.w, pv.w, su);
        float sd = av.x * dv.x;
        sd = fmaf(av.y, dv.y, sd); sd = fmaf(av.z, dv.z, sd); sd = fmaf(av.w, dv.w, sd);
        su += __shfl_xor(su, 1, 64); su += __shfl_xor(su, 2, 64);
        sd += __shfl_xor(sd, 1, 64); sd += __shfl_xor(sd, 2, 64);
        if (q3 == 0) {
            es0w[w * 16 + m3] = su + ((m3 == 0) ? sS : 0.f);
            ed0w[w * 16 + m3] = sd + ((m3 == 0) ? dS : 0.f);
        }
    }
    // P4 (64 lanes, wave-synchronous): alpha0 row j, s-quarter q
    {
        const int j = lane >> 2, q = lane & 3;
        const float ej = ed0w[w * 16 + j];
        const float4 ev = ((const float4*)(es0w + w * 16))[q];
        float e0 = ev.x + ej; e0 = (e0 >= 0.f) ? e0 : 0.2f * e0;
        float e1 = ev.y + ej; e1 = (e1 >= 0.f) ? e1 : 0.2f * e1;
        float e2 = ev.z + ej; e2 = (e2 >= 0.f) ? e2 : 0.2f * e2;
        float e3 = ev.w + ej; e3 = (e3 >= 0.f) ? e3 : 0.2f * e3;
        float mx = fmaxf(fmaxf(e0, e1), fmaxf(e2, e3));
        mx = fmaxf(mx, __shfl_xor(mx, 1, 64));
        mx = fmaxf(mx, __shfl_xor(mx, 2, 64));
        e0 = __expf(e0 - mx); e1 = __expf(e1 - mx);
        e2 = __expf(e2 - mx); e3 = __expf(e3 - mx);
        float s = e0 + e1 + e2 + e3;
        s += __shfl_xor(s, 1, 64); s += __shfl_xor(s, 2, 64);
        float inv = 1.f / s;
        ((float4*)(a0L + (w << 8) + j * 16))[q] =
            make_float4(e0 * inv, e1 * inv, e2 * inv, e3 * inv);
    }
    // a0L[w] written and consumed by wave w only -> no block barrier

    // P56: xl0r[s] = (s==0)*S + act[s].W0a[:,n]; x1r[j] via b128 a0L[w]
    float x1r[16];
    {
        const float4* act4 = (const float4*)actL;
        float xl0r[16];
        #pragma unroll
        for (int s = 0; s < 16; s++) {
            float a = 0.f;
            #pragma unroll
            for (int q = 0; q < 4; q++) {
                float4 av = act4[s * 4 + q];
                FMA4(a, av, wa[q]);
            }
            xl0r[s] = a;
        }
        xl0r[0] += S;
        const float b0v = b0[n];
        const float4* a04 = (const float4*)(a0L + (w << 8));
        #pragma unroll
        for (int j = 0; j < 16; j++) {
            float acc = b0v;
            #pragma unroll
            for (int s4 = 0; s4 < 4; s4++) {
                float4 a4 = a04[j * 4 + s4];          // broadcast b128
                acc = fmaf(a4.x, xl0r[s4 * 4 + 0], acc);
                acc = fmaf(a4.y, xl0r[s4 * 4 + 1], acc);
                acc = fmaf(a4.z, xl0r[s4 * 4 + 2], acc);
                acc = fmaf(a4.w, xl0r[s4 * 4 + 3], acc);
            }
            x1r[j] = fmaxf(acc, 0.f);
            x1L[j * 260 + n] = x1r[j];
        }
    }
    __syncthreads();                                       // barrier 2

    // P7: es1/ed1 partials; u1/ud1 direct from global (L1 broadcast)
    {
        const int m = tid & 15, h = (tid >> 4) & 3, p = tid >> 6;
        const float4* x4p = (const float4*)(x1L + m * 260 + p * 64);
        const float4* u4p = ((const float4*)u1g) + h * 64 + p * 16;
        float a = 0.f;
        #pragma unroll
        for (int i = 0; i < 16; i++) {
            float4 xv = x4p[i], uv = u4p[i];
            FMA4(a, xv, uv);
        }
        espL[m * 16 + h * 4 + p] = a;
        if (m == 0) {
            const float4* ud4p = ((const float4*)ud1g) + h * 64 + p * 16;
            float ad = 0.f;
            #pragma unroll
            for (int i = 0; i < 16; i++) {
                float4 xv = x4p[i], uv = ud4p[i];
                FMA4(ad, xv, uv);
            }
            edpL[h * 4 + p] = ad;
        }
    }
    __syncthreads();                                       // barrier 3

    // P8 (wave 0, wave-synchronous): es1 sums then alpha1 (16 lanes)
    if (w == 0) {
        {
            const int m2 = lane >> 2, h = lane & 3;
            const float* e = espL + m2 * 16 + h * 4;
            es1L[m2 * 4 + h] = e[0] + e[1] + e[2] + e[3];
        }
        if (lane < 16) {
            const int h = lane >> 2, q = lane & 3;
            float ej = edpL[h * 4] + edpL[h * 4 + 1] + edpL[h * 4 + 2] + edpL[h * 4 + 3];
            float e[4]; float mx = -1e30f;
            #pragma unroll
            for (int r = 0; r < 4; r++) {
                float x = es1L[(q * 4 + r) * 4 + h] + ej;
                x = (x >= 0.f) ? x : 0.2f * x;
                e[r] = x; mx = fmaxf(mx, x);
            }
            mx = fmaxf(mx, __shfl_xor(mx, 1, 64));
            mx = fmaxf(mx, __shfl_xor(mx, 2, 64));
            float s = 0.f;
            #pragma unroll
            for (int r = 0; r < 4; r++) { e[r] = __expf(e[r] - mx); s += e[r]; }
            s += __shfl_xor(s, 1, 64);
            s += __shfl_xor(s, 2, 64);
            float inv = 1.f / s;
            ((float4*)(alpha1L + h * 16 + q * 4))[0] =
                make_float4(e[0] * inv, e[1] * inv, e[2] * inv, e[3] * inv);
        }
    }
    __syncthreads();                                       // barrier 4

    // P9: z[hh][n] = sum_s alpha1[hh][s] * x1r[s]; W1 batch 0 + b1 prefetch
    const float4* W1PK4 = (const float4*)W1PK;
    float4 w1pf[8];
    #pragma unroll
    for (int j = 0; j < 8; j++) w1pf[j] = W1PK4[j * 256 + n];
    const float b1v = b1[n];
    {
        const float4* a14 = (const float4*)alpha1L;
        #pragma unroll
        for (int hh = 0; hh < 4; hh++) {
            float zv = 0.f;
            #pragma unroll
            for (int s4 = 0; s4 < 4; s4++) {
                float4 a4 = a14[hh * 4 + s4];         // broadcast b128
                zv = fmaf(a4.x, x1r[s4 * 4 + 0], zv);
                zv = fmaf(a4.y, x1r[s4 * 4 + 1], zv);
                zv = fmaf(a4.z, x1r[s4 * 4 + 2], zv);
                zv = fmaf(a4.w, x1r[s4 * 4 + 3], zv);
            }
            zL[hh * 260 + n] = zv;
        }
    }
    __syncthreads();                                       // barrier 5

    // P10: seq[bg][n] = relu(z[w] . W1[:,n] + b1[n]); k-order preserved
    {
        const float4* zh = (const float4*)(zL + w * 260);
        float acc = b1v;
        #pragma unroll
        for (int j = 0; j < 8; j++) {
            float4 z4 = zh[j];
            FMA4(acc, w1pf[j], z4);
        }
        #pragma unroll
        for (int io = 1; io < 8; io++) {
            float4 wv[8];
            #pragma unroll
            for (int j = 0; j < 8; j++) wv[j] = W1PK4[(io * 8 + j) * 256 + n];
            #pragma unroll
            for (int j = 0; j < 8; j++) {
                float4 z4 = zh[io * 8 + j];
                FMA4(acc, wv[j], z4);
            }
        }
        seqf[bg * 256 + n] = fmaxf(acc, 0.f);
    }
}

// ---------------- stage 2: qkv + attention + out_proj + heads (R17) --------
__global__ __launch_bounds__(768) void k_stage2(
    const float* __restrict__ seqf,   // (2560,256)
    const float* __restrict__ wipPK,  // packed [64][768][4]
    const float* __restrict__ bip,
    const float* __restrict__ wopPK,  // packed [64][256][4]
    const float* __restrict__ bop,
    const float* __restrict__ whPK,   // packed [64][320][4]
    const float* __restrict__ bm, const float* __restrict__ blv,
    const float* __restrict__ bb,
    float* __restrict__ out)
{
    __shared__ float sseq[2][5][256];
    __shared__ float kL[2][5][256], vL[2][5][256], qL[2][256];
    __shared__ float ctxL[2][256], featL[2][256];
    __shared__ float beliefL[2][64];
    const int tid = threadIdx.x;
    const int b0 = blockIdx.x * 2;

    {   // flat float4 copy (2560 floats = 640 float4)
        float4* sflat = (float4*)&sseq[0][0][0];
        const float4* src = (const float4*)(seqf + b0 * 1280);
        if (tid < 640) sflat[tid] = src[tid];
    }
    __syncthreads();

    // qkv: kind 0 -> q (t=4, both gb); kind 1 -> k; kind 2 -> v
    {
        const int kind = tid >> 8, n = tid & 255;
        const float4* wPK = (const float4*)wipPK + tid;    // k4 stride 768
        if (kind == 0) {
            const float4* s0 = (const float4*)&sseq[0][4][0];
            const float4* s1 = (const float4*)&sseq[1][4][0];
            float a0 = 0.f, a1 = 0.f;
            #pragma unroll 8
            for (int k4 = 0; k4 < 64; k4++) {
                float4 wv = wPK[k4 * 768];
                float4 x0 = s0[k4], x1 = s1[k4];
                a0 = fmaf(x0.x, wv.x, a0); a0 = fmaf(x0.y, wv.y, a0);
                a0 = fmaf(x0.z, wv.z, a0); a0 = fmaf(x0.w, wv.w, a0);
                a1 = fmaf(x1.x, wv.x, a1); a1 = fmaf(x1.y, wv.y, a1);
                a1 = fmaf(x1.z, wv.z, a1); a1 = fmaf(x1.w, wv.w, a1);
            }
            float bv = bip[n];
            qL[0][n] = a0 + bv; qL[1][n] = a1 + bv;
        } else {
            float acc[2][5] = {{0.f,0.f,0.f,0.f,0.f},{0.f,0.f,0.f,0.f,0.f}};
            #pragma unroll 4
            for (int k4 = 0; k4 < 64; k4++) {
                float4 wv = wPK[k4 * 768];
                #pragma unroll
                for (int gb = 0; gb < 2; gb++) {
                    #pragma unroll
                    for (int t = 0; t < 5; t++) {
                        float4 sv = ((const float4*)&sseq[gb][t][0])[k4];
                        float a = acc[gb][t];
                        a = fmaf(sv.x, wv.x, a); a = fmaf(sv.y, wv.y, a);
                        a = fmaf(sv.z, wv.z, a); a = fmaf(sv.w, wv.w, a);
                        acc[gb][t] = a;
                    }
                }
            }
            float bv = bip[kind * 256 + n];
            float* dst = (kind == 1) ? &kL[0][0][0] : &vL[0][0][0];
            #pragma unroll
            for (int gb = 0; gb < 2; gb++)
                #pragma unroll
                for (int t = 0; t < 5; t++)
                    dst[gb * 1280 + t * 256 + n] = acc[gb][t] + bv;
        }
    }
    __syncthreads();

    // attention at q=4 (causal mask constant -> cancels)
    if (tid < 512) {
        const int gb = tid >> 8, col = tid & 255;
        float q4 = qL[gb][col];
        float sc[5];
        #pragma unroll
        for (int t = 0; t < 5; t++)
            sc[t] = wave_sum64(q4 * kL[gb][t][col]) * 0.125f;
        float m = sc[0];
        #pragma unroll
        for (int t = 1; t < 5; t++) m = fmaxf(m, sc[t]);
        float p[5], sum = 0.f;
        #pragma unroll
        for (int t = 0; t < 5; t++) { p[t] = __expf(sc[t] - m); sum += p[t]; }
        float inv = 1.f / sum, cv = 0.f;
        #pragma unroll
        for (int t = 0; t < 5; t++) cv = fmaf(p[t], vL[gb][t][col], cv);
        ctxL[gb][col] = cv * inv;
    }
    __syncthreads();

    // out_proj (float4 packed)
    if (tid < 512) {
        const int gb = tid >> 8, n = tid & 255;
        const float4* wPK = (const float4*)wopPK + n;
        const float4* c4 = (const float4*)&ctxL[gb][0];
        float acc = 0.f;
        #pragma unroll 8
        for (int k4 = 0; k4 < 64; k4++) {
            float4 wv = wPK[k4 * 256], cv = c4[k4];
            FMA4(acc, wv, cv);
        }
        featL[gb][n] = acc + bop[n];
    }
    __syncthreads();

    // heads: j in [0,320) for both gb (float4 packed)
    if (tid < 640) {
        const int gb = tid / 320, j = tid - gb * 320;
        const float4* wPK = (const float4*)whPK + j;
        const float4* f4 = (const float4*)&featL[gb][0];
        float acc = 0.f;
        #pragma unroll 8
        for (int k4 = 0; k4 < 64; k4++) {
            float4 wv = wPK[k4 * 320], fv = f4[k4];
            FMA4(acc, wv, fv);
        }
        if (j < 128) {
            out[(b0 + gb) * 128 + j] = acc + bm[j];
        } else if (j < 256) {
            out[65536 + (b0 + gb) * 128 + (j - 128)] = acc + blv[j - 128];
        } else {
            beliefL[gb][j - 256] = acc + bb[j - 256];
        }
    }
    __syncthreads();

    // belief softmax: wave 0 -> gb 0, wave 1 -> gb 1
    if (tid < 128) {
        int gb = tid >> 6, lane = tid & 63;
        float lg = beliefL[gb][lane];
        float m = wave_max64(lg);
        float e = __expf(lg - m);
        float s = wave_sum64(e);
        out[131072 + (b0 + gb) * 64 + lane] = e / s;
    }
}

// ---------------------------------------------------------------------------
extern "C" void kernel_launch(void* const* d_in, const int* in_sizes, int n_in,
                              void* d_out, int out_size, void* d_ws, size_t ws_size,
                              hipStream_t stream) {
    const float* sig  = (const float*)d_in[0];
    const float* nact = (const float*)d_in[1];
    const float* w0   = (const float*)d_in[2];
    const float* as0  = (const float*)d_in[3];
    const float* ad0  = (const float*)d_in[4];
    const float* b0   = (const float*)d_in[5];
    const float* w1   = (const float*)d_in[6];
    const float* as1  = (const float*)d_in[7];
    const float* ad1  = (const float*)d_in[8];
    const float* b1   = (const float*)d_in[9];
    const float* wip  = (const float*)d_in[10];
    const float* bip  = (const float*)d_in[11];
    const float* wop  = (const float*)d_in[12];
    const float* bop  = (const float*)d_in[13];
    const float* wm   = (const float*)d_in[14];
    const float* bm   = (const float*)d_in[15];
    const float* wlv  = (const float*)d_in[16];
    const float* blv  = (const float*)d_in[17];
    const float* wb   = (const float*)d_in[18];
    const float* bb   = (const float*)d_in[19];
    // d_in[20] = edge_index (deterministic complete graph) — unused.

    // ws layout (floats): seqf + packed transposes + folds. ~4.35 MB
    float* ws    = (float*)d_ws;
    float* seqf  = ws;                 // 655360
    float* tws   = ws + 655360;        // 430080:
    float* W0sPK = tws;                //   16384
    float* W0aPK = tws + 16384;        //   4096
    float* W1PK  = tws + 20480;        //   65536
    float* wipPK = tws + 86016;        //   196608
    float* wopPK = tws + 282624;       //   65536
    float* whPK  = tws + 348160;       //   81920
    float* u1    = ws + 1085440;       // 1024
    float* ud1   = ws + 1086464;       // 1024
    float* pa0   = ws + 1087488;       // 64
    float* pd0   = ws + 1087552;       // 64

    k_pre   <<<1685, 256, 0, stream>>>(w0, w1, wip, wop, wm, wlv, wb,
                                       as0, ad0, as1, ad1,
                                       tws, u1, ud1, pa0, pd0);
    k_gat   <<<2560, 256, 0, stream>>>(sig, nact, W0sPK, W0aPK, W1PK,
                                       u1, ud1, pa0, pd0, as0, ad0, b0, b1, seqf);
    k_stage2<<<256, 768, 0, stream>>>(seqf, wipPK, bip, wopPK, bop, whPK,
                                      bm, blv, bb, (float*)d_out);
}